// Round 1
// baseline (1299.188 us; speedup 1.0000x reference)
//
#include <hip/hip_runtime.h>
#include <hip/hip_bf16.h>

// Problem constants
#define HH 40
#define WW 40
#define KK 5
#define HOUT 36
#define WOUTc 36
#define PP 1296            // HOUT*WOUT
#define LL 25              // K*K*C
#define MM 384
#define NN 64
#define NPTS (NN * PP)     // 82944
#define JITTER 1e-6f
#define TP 32              // points per workgroup in main kernel
#define NEWTON_ITERS 14

// ---------------------------------------------------------------------------
// Kuu[i][j] = var * exp(-0.5*||Zi-Zj||^2/ls^2) + jitter*I
__global__ void kuu_kernel(const float* __restrict__ Z,
                           const float* __restrict__ var_p,
                           const float* __restrict__ ls_p,
                           float* __restrict__ Kuu) {
    int idx = blockIdx.x * 256 + threadIdx.x;
    if (idx >= MM * MM) return;
    int i = idx / MM, j = idx % MM;
    float s = 0.0f;
#pragma unroll
    for (int l = 0; l < LL; ++l) {
        float d = Z[i * LL + l] - Z[j * LL + l];
        s += d * d;
    }
    float ls = ls_p[0];
    float v = var_p[0] * expf(-0.5f * s / (ls * ls));
    if (i == j) v += JITTER;
    Kuu[idx] = v;
}

// ---------------------------------------------------------------------------
// alpha = 1 / max_i sum_j Kuu[i][j]   (Gershgorin bound on lambda_max)
__global__ void rowmax_kernel(const float* __restrict__ Kuu,
                              float* __restrict__ alpha) {
    __shared__ float red[256];
    float mx = 0.0f;
    for (int r = threadIdx.x; r < MM; r += 256) {
        float s = 0.0f;
        for (int j = 0; j < MM; ++j) s += Kuu[r * MM + j];
        mx = fmaxf(mx, s);
    }
    red[threadIdx.x] = mx;
    __syncthreads();
    for (int off = 128; off > 0; off >>= 1) {
        if (threadIdx.x < off)
            red[threadIdx.x] = fmaxf(red[threadIdx.x], red[threadIdx.x + off]);
        __syncthreads();
    }
    if (threadIdx.x == 0) alpha[0] = 1.0f / red[0];
}

// X0 = alpha * I
__global__ void xinit_kernel(float* __restrict__ X0,
                             const float* __restrict__ alpha) {
    int idx = blockIdx.x * 256 + threadIdx.x;
    if (idx >= MM * MM) return;
    int i = idx / MM, j = idx % MM;
    X0[idx] = (i == j) ? alpha[0] : 0.0f;
}

// ---------------------------------------------------------------------------
// Generic 384x384 GEMM, 32x32 tiles. mode 0: C = A@B ; mode 1: C = 2*A - A@B
__global__ void gemm384_kernel(const float* __restrict__ A,
                               const float* __restrict__ B,
                               float* __restrict__ C, int mode) {
    __shared__ float As[32][33];
    __shared__ float Bs[32][33];
    int bi = blockIdx.y, bj = blockIdx.x;
    int tid = threadIdx.x;
    int ty = tid / 16, tx = tid % 16;
    float acc00 = 0.f, acc01 = 0.f, acc10 = 0.f, acc11 = 0.f;
    for (int kt = 0; kt < MM / 32; ++kt) {
#pragma unroll
        for (int e = tid; e < 1024; e += 256) {
            int r = e / 32, cc = e % 32;
            As[r][cc] = A[(bi * 32 + r) * MM + kt * 32 + cc];
            Bs[r][cc] = B[(kt * 32 + r) * MM + bj * 32 + cc];
        }
        __syncthreads();
#pragma unroll
        for (int kk = 0; kk < 32; ++kk) {
            float a0 = As[2 * ty][kk], a1 = As[2 * ty + 1][kk];
            float b0 = Bs[kk][2 * tx], b1 = Bs[kk][2 * tx + 1];
            acc00 += a0 * b0; acc01 += a0 * b1;
            acc10 += a1 * b0; acc11 += a1 * b1;
        }
        __syncthreads();
    }
    int gi0 = bi * 32 + 2 * ty, gj0 = bj * 32 + 2 * tx;
    float vals[2][2] = {{acc00, acc01}, {acc10, acc11}};
#pragma unroll
    for (int r = 0; r < 2; ++r)
#pragma unroll
        for (int cc = 0; cc < 2; ++cc) {
            int gi = gi0 + r, gj = gj0 + cc;
            float v = vals[r][cc];
            if (mode == 1) v = 2.0f * A[gi * MM + gj] - v;
            C[gi * MM + gj] = v;
        }
}

// ---------------------------------------------------------------------------
// SK = tril(q_sqrt) @ tril(q_sqrt)^T - Kuu
__global__ void sk_kernel(const float* __restrict__ qs,
                          const float* __restrict__ Kuu,
                          float* __restrict__ SK) {
    __shared__ float As[32][33];
    __shared__ float Bs[32][33];
    int bi = blockIdx.y, bj = blockIdx.x;
    int tid = threadIdx.x;
    int ty = tid / 16, tx = tid % 16;
    float acc00 = 0.f, acc01 = 0.f, acc10 = 0.f, acc11 = 0.f;
    for (int kt = 0; kt < MM / 32; ++kt) {
#pragma unroll
        for (int e = tid; e < 1024; e += 256) {
            int r = e / 32, cc = e % 32;
            int kcol = kt * 32 + cc;
            int arow = bi * 32 + r;
            int brow = bj * 32 + r;
            As[r][cc] = (kcol <= arow) ? qs[arow * MM + kcol] : 0.0f;
            Bs[r][cc] = (kcol <= brow) ? qs[brow * MM + kcol] : 0.0f;
        }
        __syncthreads();
#pragma unroll
        for (int kk = 0; kk < 32; ++kk) {
            float a0 = As[2 * ty][kk], a1 = As[2 * ty + 1][kk];
            float b0 = Bs[2 * tx][kk], b1 = Bs[2 * tx + 1][kk];
            acc00 += a0 * b0; acc01 += a0 * b1;
            acc10 += a1 * b0; acc11 += a1 * b1;
        }
        __syncthreads();
    }
    int gi0 = bi * 32 + 2 * ty, gj0 = bj * 32 + 2 * tx;
    float vals[2][2] = {{acc00, acc01}, {acc10, acc11}};
#pragma unroll
    for (int r = 0; r < 2; ++r)
#pragma unroll
        for (int cc = 0; cc < 2; ++cc) {
            int gi = gi0 + r, gj = gj0 + cc;
            SK[gi * MM + gj] = vals[r][cc] - Kuu[gi * MM + gj];
        }
}

// ---------------------------------------------------------------------------
// y = A @ x  (384x384 times 384-vector); one wave per row
__global__ void gemv384_kernel(const float* __restrict__ A,
                               const float* __restrict__ x,
                               float* __restrict__ y) {
    int row = blockIdx.x;
    int lane = threadIdx.x;
    float s = 0.0f;
    for (int j = lane; j < MM; j += 64) s += A[row * MM + j] * x[j];
#pragma unroll
    for (int off = 32; off > 0; off >>= 1) s += __shfl_down(s, off);
    if (lane == 0) y[row] = s;
}

// ---------------------------------------------------------------------------
// Main fused kernel: per 32 output points build k-vector tile in LDS, then
// mean[p] = c . k_p ; diag[p] = k_p^T B k_p via register-tiled fp32 GEMM.
__global__ void __launch_bounds__(256)
main_kernel(const float* __restrict__ Xin, const float* __restrict__ Z,
            const float* __restrict__ Bm, const float* __restrict__ cvec,
            const float* __restrict__ var_p, const float* __restrict__ ls_p,
            float* __restrict__ out) {
    __shared__ __align__(16) float Ktile[MM * TP];  // [m][p], stride 32
    __shared__ __align__(16) float red[1024];       // patch staging + reductions
    int tid = threadIdx.x;
    int np0 = blockIdx.x * TP;
    float var = var_p[0];
    float ls = ls_p[0];
    float inv2ls2 = -0.5f / (ls * ls);

    // phase 1a: stage patches [32][26] (stride 26 to dodge bank conflicts)
    float* patch = red;
    for (int e = tid; e < TP * LL; e += 256) {
        int pt = e / LL, l = e % LL;
        int np = np0 + pt;
        int n = np / PP, p = np % PP;
        int oi = p / WOUTc, oj = p % WOUTc;
        int ki = l / KK, kj = l % KK;
        patch[pt * 26 + l] = Xin[n * (HH * WW) + (oi + ki) * WW + (oj + kj)];
    }
    __syncthreads();

    // phase 1b: K tile: Ktile[m][p] = var*exp(-0.5*||Z_m - patch_p||^2/ls^2)
    for (int e = tid; e < MM * TP; e += 256) {
        int m = e >> 5;
        int p = e & 31;
        float s = 0.0f;
#pragma unroll
        for (int l = 0; l < LL; ++l) {
            float d = Z[m * LL + l] - patch[p * 26 + l];
            s += d * d;
        }
        Ktile[m * TP + p] = var * __expf(s * inv2ls2);
    }
    __syncthreads();

    // phase 2: acc[i][j] = sum_k B[m0+i][k] * Ktile[k][p0+j]
    int rg = tid >> 3;   // 0..31  -> rows m0..m0+11
    int pg = tid & 7;    // 0..7   -> cols p0..p0+3
    int m0 = rg * 12;
    int p0 = pg * 4;
    float acc[12][4] = {};
    for (int k = 0; k < MM; k += 4) {
        float4 kv0 = *(const float4*)&Ktile[(k + 0) * TP + p0];
        float4 kv1 = *(const float4*)&Ktile[(k + 1) * TP + p0];
        float4 kv2 = *(const float4*)&Ktile[(k + 2) * TP + p0];
        float4 kv3 = *(const float4*)&Ktile[(k + 3) * TP + p0];
#pragma unroll
        for (int i = 0; i < 12; ++i) {
            float4 bv = *(const float4*)&Bm[(m0 + i) * MM + k];
            acc[i][0] += bv.x * kv0.x + bv.y * kv1.x + bv.z * kv2.x + bv.w * kv3.x;
            acc[i][1] += bv.x * kv0.y + bv.y * kv1.y + bv.z * kv2.y + bv.w * kv3.y;
            acc[i][2] += bv.x * kv0.z + bv.y * kv1.z + bv.z * kv2.z + bv.w * kv3.z;
            acc[i][3] += bv.x * kv0.w + bv.y * kv1.w + bv.z * kv2.w + bv.w * kv3.w;
        }
    }

    // epilogue partials
    float meanp[4] = {0.f, 0.f, 0.f, 0.f};
    float diagp[4] = {0.f, 0.f, 0.f, 0.f};
#pragma unroll
    for (int i = 0; i < 12; ++i) {
        float ci = cvec[m0 + i];
#pragma unroll
        for (int j = 0; j < 4; ++j) {
            float kval = Ktile[(m0 + i) * TP + p0 + j];
            meanp[j] += ci * kval;
            diagp[j] += kval * acc[i][j];
        }
    }

    // reduce diag across the 32 row-groups
    __syncthreads();
#pragma unroll
    for (int j = 0; j < 4; ++j) red[rg * 32 + p0 + j] = diagp[j];
    __syncthreads();
    if (tid < TP) {
        float s = 0.0f;
        for (int r = 0; r < 32; ++r) s += red[r * 32 + tid];
        out[NPTS + np0 + tid] = var + s;  // var output
    }
    __syncthreads();
#pragma unroll
    for (int j = 0; j < 4; ++j) red[rg * 32 + p0 + j] = meanp[j];
    __syncthreads();
    if (tid < TP) {
        float s = 0.0f;
        for (int r = 0; r < 32; ++r) s += red[r * 32 + tid];
        out[np0 + tid] = s;  // mean output
    }
}

// ---------------------------------------------------------------------------
extern "C" void kernel_launch(void* const* d_in, const int* in_sizes, int n_in,
                              void* d_out, int out_size, void* d_ws, size_t ws_size,
                              hipStream_t stream) {
    const float* Xin   = (const float*)d_in[0];
    const float* Z     = (const float*)d_in[1];
    const float* q_mu  = (const float*)d_in[2];
    const float* q_sqrt= (const float*)d_in[3];
    const float* var_p = (const float*)d_in[4];
    const float* ls_p  = (const float*)d_in[5];
    float* out = (float*)d_out;

    float* ws = (float*)d_ws;
    const int MAT = MM * MM;  // 147456
    float* Kuu  = ws;
    float* Xa   = ws + 1 * MAT;
    float* Xb   = ws + 2 * MAT;
    float* Yb   = ws + 3 * MAT;
    float* SKm  = ws + 4 * MAT;
    float* cvec = ws + 5 * MAT;
    float* alpha = cvec + MM;

    // 1) Kuu
    kuu_kernel<<<(MAT + 255) / 256, 256, 0, stream>>>(Z, var_p, ls_p, Kuu);
    // 2) alpha = 1/max row sum ; X0 = alpha*I
    rowmax_kernel<<<1, 256, 0, stream>>>(Kuu, alpha);
    xinit_kernel<<<(MAT + 255) / 256, 256, 0, stream>>>(Xa, alpha);
    // 3) Newton-Schulz: X' = 2X - X(Kuu X)
    dim3 ggrid(MM / 32, MM / 32);
    float* cur = Xa;
    float* oth = Xb;
    for (int it = 0; it < NEWTON_ITERS; ++it) {
        gemm384_kernel<<<ggrid, 256, 0, stream>>>(Kuu, cur, Yb, 0);
        gemm384_kernel<<<ggrid, 256, 0, stream>>>(cur, Yb, oth, 1);
        float* t = cur; cur = oth; oth = t;
    }
    // NEWTON_ITERS even -> cur == Xa holds Kuu^{-1}
    // 4) SK = tril(q_sqrt) tril(q_sqrt)^T - Kuu
    sk_kernel<<<ggrid, 256, 0, stream>>>(q_sqrt, Kuu, SKm);
    // 5) B = inv @ SK @ inv   (Yb = inv@SK ; Xb = Yb@inv)
    gemm384_kernel<<<ggrid, 256, 0, stream>>>(cur, SKm, Yb, 0);
    gemm384_kernel<<<ggrid, 256, 0, stream>>>(Yb, cur, Xb, 0);
    // 6) c = inv @ q_mu
    gemv384_kernel<<<MM, 64, 0, stream>>>(cur, q_mu, cvec);
    // 7) fused main kernel
    main_kernel<<<NPTS / TP, 256, 0, stream>>>(Xin, Z, Xb, cvec, var_p, ls_p, out);
}

// Round 2
// 595.429 us; speedup vs baseline: 2.1819x; 2.1819x over previous
//
#include <hip/hip_runtime.h>
#include <hip/hip_bf16.h>

// Problem constants
#define HH 40
#define WW 40
#define KK 5
#define HOUT 36
#define WOUTc 36
#define PP 1296            // HOUT*WOUT
#define LL 25              // K*K*C
#define MM 384
#define NN 64
#define NPTS (NN * PP)     // 82944
#define JITTER 1e-6f
#define TP 32              // points per workgroup in main kernel
#define NEWTON_ITERS 14

using short8  = __attribute__((ext_vector_type(8))) short;
using floatx4 = __attribute__((ext_vector_type(4))) float;

// ---------------------------------------------------------------------------
// bf16 split helpers (RNE)
__device__ inline unsigned short f2bf(float v) {
    unsigned b = __float_as_uint(v);
    return (unsigned short)((b + 0x7FFFu + ((b >> 16) & 1u)) >> 16);
}
__device__ inline float bf2f(unsigned short h) {
    return __uint_as_float(((unsigned)h) << 16);
}
__device__ inline void split_bf16(float v, unsigned short& hi, unsigned short& lo) {
    hi = f2bf(v);
    lo = f2bf(v - bf2f(hi));
}

// MFMA fragment offset for contraction index k (0..383) and point column p (0..31).
// Layout: [kt(12)][nt(2)][lane(64)][j(8)]
__device__ inline int frag_off(int k, int p) {
    return (((k >> 5) * 2 + (p >> 4)) * 64 + (((k >> 3) & 3) * 16 + (p & 15))) * 8 + (k & 7);
}

// ---------------------------------------------------------------------------
// Kuu[i][j] = var * exp(-0.5*||Zi-Zj||^2/ls^2) + jitter*I
__global__ void kuu_kernel(const float* __restrict__ Z,
                           const float* __restrict__ var_p,
                           const float* __restrict__ ls_p,
                           float* __restrict__ Kuu) {
    int idx = blockIdx.x * 256 + threadIdx.x;
    if (idx >= MM * MM) return;
    int i = idx / MM, j = idx % MM;
    float s = 0.0f;
#pragma unroll
    for (int l = 0; l < LL; ++l) {
        float d = Z[i * LL + l] - Z[j * LL + l];
        s += d * d;
    }
    float ls = ls_p[0];
    float v = var_p[0] * expf(-0.5f * s / (ls * ls));
    if (i == j) v += JITTER;
    Kuu[idx] = v;
}

// ---------------------------------------------------------------------------
// alpha = 1 / max_i sum_j Kuu[i][j]   (Gershgorin bound on lambda_max)
__global__ void rowmax_kernel(const float* __restrict__ Kuu,
                              float* __restrict__ alpha) {
    __shared__ float red[256];
    float mx = 0.0f;
    for (int r = threadIdx.x; r < MM; r += 256) {
        float s = 0.0f;
        for (int j = 0; j < MM; ++j) s += Kuu[r * MM + j];
        mx = fmaxf(mx, s);
    }
    red[threadIdx.x] = mx;
    __syncthreads();
    for (int off = 128; off > 0; off >>= 1) {
        if (threadIdx.x < off)
            red[threadIdx.x] = fmaxf(red[threadIdx.x], red[threadIdx.x + off]);
        __syncthreads();
    }
    if (threadIdx.x == 0) alpha[0] = 1.0f / red[0];
}

// X0 = alpha*I ; R0 = I - alpha*Kuu
__global__ void init_kernel(const float* __restrict__ Kuu,
                            const float* __restrict__ alpha,
                            float* __restrict__ X0, float* __restrict__ R0) {
    int idx = blockIdx.x * 256 + threadIdx.x;
    if (idx >= MM * MM) return;
    int i = idx / MM, j = idx % MM;
    float a = alpha[0];
    X0[idx] = (i == j) ? a : 0.0f;
    R0[idx] = ((i == j) ? 1.0f : 0.0f) - a * Kuu[idx];
}

// ---------------------------------------------------------------------------
// 64x64-tile fp32 GEMM body: acc[4][4] += A[bi-tile] @ B[bj-tile]
__device__ inline void gemm64_body(const float* __restrict__ A,
                                   const float* __restrict__ B,
                                   int bi, int bj, float acc[4][4]) {
    __shared__ float AsT[32][68];  // [k][row] (transposed A tile)
    __shared__ float Bs[32][68];   // [k][col]
    int tid = threadIdx.x;
    int ty = tid >> 4, tx = tid & 15;
    for (int kt = 0; kt < 12; ++kt) {
        // stage A transposed: 2 float4 per thread
        {
            int row = tid >> 2;
#pragma unroll
            for (int i = 0; i < 2; ++i) {
                int kq = (tid & 3) + 4 * i;
                float4 av = *(const float4*)&A[(bi * 64 + row) * MM + kt * 32 + kq * 4];
                AsT[kq * 4 + 0][row] = av.x;
                AsT[kq * 4 + 1][row] = av.y;
                AsT[kq * 4 + 2][row] = av.z;
                AsT[kq * 4 + 3][row] = av.w;
            }
        }
        // stage B: 2 float4 per thread
        {
            int c4 = tid & 15;
#pragma unroll
            for (int i = 0; i < 2; ++i) {
                int kk = (tid >> 4) + 16 * i;
                *(float4*)&Bs[kk][c4 * 4] =
                    *(const float4*)&B[(kt * 32 + kk) * MM + bj * 64 + c4 * 4];
            }
        }
        __syncthreads();
#pragma unroll
        for (int kk = 0; kk < 32; ++kk) {
            float4 a = *(const float4*)&AsT[kk][4 * ty];
            float4 b = *(const float4*)&Bs[kk][4 * tx];
            float av[4] = {a.x, a.y, a.z, a.w};
            float bv[4] = {b.x, b.y, b.z, b.w};
#pragma unroll
            for (int r = 0; r < 4; ++r)
#pragma unroll
                for (int c = 0; c < 4; ++c) acc[r][c] += av[r] * bv[c];
        }
        __syncthreads();
    }
}

// One Newton-Schulz round in ONE launch: blocks 0..35 -> Xn = X + X@R,
// blocks 36..71 -> Rn = R@R.
__global__ void __launch_bounds__(256) ns_round_kernel(
    const float* __restrict__ X, const float* __restrict__ R,
    float* __restrict__ Xn, float* __restrict__ Rn) {
    int t = blockIdx.x;
    bool isX = t < 36;
    int tile = isX ? t : t - 36;
    int bi = tile / 6, bj = tile % 6;
    float acc[4][4] = {};
    gemm64_body(isX ? X : R, R, bi, bj, acc);
    int ty = threadIdx.x >> 4, tx = threadIdx.x & 15;
    float* D = isX ? Xn : Rn;
#pragma unroll
    for (int r = 0; r < 4; ++r)
#pragma unroll
        for (int c = 0; c < 4; ++c) {
            int gi = bi * 64 + 4 * ty + r, gj = bj * 64 + 4 * tx + c;
            float v = acc[r][c];
            if (isX) v += X[gi * MM + gj];
            D[gi * MM + gj] = v;
        }
}

// Plain C = A @ B, grid 36
__global__ void __launch_bounds__(256) gemm64_kernel(
    const float* __restrict__ A, const float* __restrict__ B,
    float* __restrict__ C) {
    int bi = blockIdx.x / 6, bj = blockIdx.x % 6;
    float acc[4][4] = {};
    gemm64_body(A, B, bi, bj, acc);
    int ty = threadIdx.x >> 4, tx = threadIdx.x & 15;
#pragma unroll
    for (int r = 0; r < 4; ++r)
#pragma unroll
        for (int c = 0; c < 4; ++c)
            C[(bi * 64 + 4 * ty + r) * MM + bj * 64 + 4 * tx + c] = acc[r][c];
}

// ---------------------------------------------------------------------------
// SK = tril(q_sqrt) @ tril(q_sqrt)^T - Kuu
__global__ void sk_kernel(const float* __restrict__ qs,
                          const float* __restrict__ Kuu,
                          float* __restrict__ SK) {
    __shared__ float As[32][33];
    __shared__ float Bs[32][33];
    int bi = blockIdx.y, bj = blockIdx.x;
    int tid = threadIdx.x;
    int ty = tid / 16, tx = tid % 16;
    float acc00 = 0.f, acc01 = 0.f, acc10 = 0.f, acc11 = 0.f;
    for (int kt = 0; kt < MM / 32; ++kt) {
#pragma unroll
        for (int e = tid; e < 1024; e += 256) {
            int r = e / 32, cc = e % 32;
            int kcol = kt * 32 + cc;
            int arow = bi * 32 + r;
            int brow = bj * 32 + r;
            As[r][cc] = (kcol <= arow) ? qs[arow * MM + kcol] : 0.0f;
            Bs[r][cc] = (kcol <= brow) ? qs[brow * MM + kcol] : 0.0f;
        }
        __syncthreads();
#pragma unroll
        for (int kk = 0; kk < 32; ++kk) {
            float a0 = As[2 * ty][kk], a1 = As[2 * ty + 1][kk];
            float b0 = Bs[2 * tx][kk], b1 = Bs[2 * tx + 1][kk];
            acc00 += a0 * b0; acc01 += a0 * b1;
            acc10 += a1 * b0; acc11 += a1 * b1;
        }
        __syncthreads();
    }
    int gi0 = bi * 32 + 2 * ty, gj0 = bj * 32 + 2 * tx;
    float vals[2][2] = {{acc00, acc01}, {acc10, acc11}};
#pragma unroll
    for (int r = 0; r < 2; ++r)
#pragma unroll
        for (int cc = 0; cc < 2; ++cc) {
            int gi = gi0 + r, gj = gj0 + cc;
            SK[gi * MM + gj] = vals[r][cc] - Kuu[gi * MM + gj];
        }
}

// ---------------------------------------------------------------------------
// y = A @ x  (384x384 times 384-vector); one wave per row
__global__ void gemv384_kernel(const float* __restrict__ A,
                               const float* __restrict__ x,
                               float* __restrict__ y) {
    int row = blockIdx.x;
    int lane = threadIdx.x;
    float s = 0.0f;
    for (int j = lane; j < MM; j += 64) s += A[row * MM + j] * x[j];
#pragma unroll
    for (int off = 32; off > 0; off >>= 1) s += __shfl_down(s, off);
    if (lane == 0) y[row] = s;
}

// ---------------------------------------------------------------------------
// Convert Bq (fp32 [384][384]) into MFMA A-fragment order bf16 hi/lo.
// Layout: [mtile(24)][kt(12)][lane(64)][j(8)], element (m,k):
//   m = mtile*16 + (lane&15), k = kt*32 + (lane>>4)*8 + j
__global__ void convert_kernel(const float* __restrict__ Bq,
                               unsigned short* __restrict__ Bfh,
                               unsigned short* __restrict__ Bfl) {
    int o = blockIdx.x * 256 + threadIdx.x;
    if (o >= MM * MM) return;
    int j = o & 7;
    int ln = (o >> 3) & 63;
    int kt = (o >> 9) % 12;
    int mtile = o / 6144;
    int k = kt * 32 + ((ln >> 4) << 3) + j;
    int m = mtile * 16 + (ln & 15);
    unsigned short hi, lo;
    split_bf16(Bq[m * MM + k], hi, lo);
    Bfh[o] = hi;
    Bfl[o] = lo;
}

// ---------------------------------------------------------------------------
// Main fused kernel (split-bf16 MFMA):
//  phase 1: build K tile [384 x 32] as bf16 hi/lo directly in fragment order
//  phase 2: acc[m][p] = sum_k Bq[m][k]*K[k][p] via 3-term mfma_f32_16x16x32_bf16
//  epilogue: diag[p] = sum_m K[m][p]*acc[m][p]; mean[p] = sum_m c[m]*K[m][p]
__global__ void __launch_bounds__(256) main_kernel(
    const float* __restrict__ Xin, const float* __restrict__ Z,
    const unsigned short* __restrict__ Bfh, const unsigned short* __restrict__ Bfl,
    const float* __restrict__ cvec, const float* __restrict__ var_p,
    const float* __restrict__ ls_p, float* __restrict__ out) {
    __shared__ float patch[TP * 26];
    __shared__ unsigned short kh[12 * 2 * 64 * 8];  // 12288
    __shared__ unsigned short kl[12 * 2 * 64 * 8];
    __shared__ float red[8 * 32];

    int tid = threadIdx.x;
    int np0 = blockIdx.x * TP;
    float var = var_p[0];
    float ls = ls_p[0];
    float c0 = -0.5f / (ls * ls);

    // phase 1a: stage patches [32][26]
    for (int e = tid; e < TP * LL; e += 256) {
        int pt = e / LL, l = e % LL;
        int np = np0 + pt;
        int n = np / PP, p = np % PP;
        int oi = p / WOUTc, oj = p % WOUTc;
        int ki = l / KK, kj = l % KK;
        patch[pt * 26 + l] = Xin[n * (HH * WW) + (oi + ki) * WW + (oj + kj)];
    }
    __syncthreads();

    // phase 1b: K[k][p] -> bf16 hi/lo in fragment order
#pragma unroll 4
    for (int it = 0; it < 48; ++it) {
        int e = tid + it * 256;   // 48*256 == 12288 exactly
        int k = e >> 5, p = e & 31;
        float s = 0.0f;
#pragma unroll
        for (int l = 0; l < LL; ++l) {
            float d = Z[k * LL + l] - patch[p * 26 + l];
            s += d * d;
        }
        float v = var * __expf(s * c0);
        unsigned short hi, lo;
        split_bf16(v, hi, lo);
        int o = frag_off(k, p);
        kh[o] = hi;
        kl[o] = lo;
    }
    __syncthreads();

    // phase 2: MFMA. wave w owns m-tiles [w*6, w*6+6), both n-tiles.
    int w = tid >> 6, l = tid & 63;
    floatx4 acc[6][2];
#pragma unroll
    for (int mt = 0; mt < 6; ++mt)
#pragma unroll
        for (int nt = 0; nt < 2; ++nt) {
            floatx4 z = {0.f, 0.f, 0.f, 0.f};
            acc[mt][nt] = z;
        }

    for (int kt = 0; kt < 12; ++kt) {
        short8 bh0 = *(const short8*)&kh[((kt * 2 + 0) * 64 + l) * 8];
        short8 bh1 = *(const short8*)&kh[((kt * 2 + 1) * 64 + l) * 8];
        short8 bl0 = *(const short8*)&kl[((kt * 2 + 0) * 64 + l) * 8];
        short8 bl1 = *(const short8*)&kl[((kt * 2 + 1) * 64 + l) * 8];
#pragma unroll
        for (int mt = 0; mt < 6; ++mt) {
            int mtile = w * 6 + mt;
            short8 ah = *(const short8*)&Bfh[((mtile * 12 + kt) * 64 + l) * 8];
            short8 al = *(const short8*)&Bfl[((mtile * 12 + kt) * 64 + l) * 8];
            acc[mt][0] = __builtin_amdgcn_mfma_f32_16x16x32_bf16(ah, bh0, acc[mt][0], 0, 0, 0);
            acc[mt][0] = __builtin_amdgcn_mfma_f32_16x16x32_bf16(ah, bl0, acc[mt][0], 0, 0, 0);
            acc[mt][0] = __builtin_amdgcn_mfma_f32_16x16x32_bf16(al, bh0, acc[mt][0], 0, 0, 0);
            acc[mt][1] = __builtin_amdgcn_mfma_f32_16x16x32_bf16(ah, bh1, acc[mt][1], 0, 0, 0);
            acc[mt][1] = __builtin_amdgcn_mfma_f32_16x16x32_bf16(ah, bl1, acc[mt][1], 0, 0, 0);
            acc[mt][1] = __builtin_amdgcn_mfma_f32_16x16x32_bf16(al, bh1, acc[mt][1], 0, 0, 0);
        }
    }

    // epilogue: diag partials. D frag: lane l, reg j -> m' = (l>>4)*4+j, p' = l&15
    float dp0 = 0.f, dp1 = 0.f;
#pragma unroll
    for (int mt = 0; mt < 6; ++mt) {
#pragma unroll
        for (int j = 0; j < 4; ++j) {
            int m = (w * 6 + mt) * 16 + ((l >> 4) << 2) + j;
            int o0 = frag_off(m, (l & 15));
            int o1 = frag_off(m, 16 + (l & 15));
            float kv0 = bf2f(kh[o0]) + bf2f(kl[o0]);
            float kv1 = bf2f(kh[o1]) + bf2f(kl[o1]);
            dp0 += kv0 * acc[mt][0][j];
            dp1 += kv1 * acc[mt][1][j];
        }
    }
    dp0 += __shfl_xor(dp0, 16); dp0 += __shfl_xor(dp0, 32);
    dp1 += __shfl_xor(dp1, 16); dp1 += __shfl_xor(dp1, 32);
    if (l < 16) {
        red[w * 32 + l] = dp0;
        red[w * 32 + 16 + l] = dp1;
    }
    __syncthreads();
    if (tid < 32) {
        float s = red[tid] + red[32 + tid] + red[64 + tid] + red[96 + tid];
        out[NPTS + np0 + tid] = var + s;
    }
    __syncthreads();

    // mean: thread (ch,p) sums 48 m's
    {
        int p = tid & 31, ch = tid >> 5;
        float s = 0.0f;
#pragma unroll 8
        for (int i = 0; i < 48; ++i) {
            int m = ch * 48 + i;
            int o = frag_off(m, p);
            s += cvec[m] * (bf2f(kh[o]) + bf2f(kl[o]));
        }
        red[ch * 32 + p] = s;
    }
    __syncthreads();
    if (tid < 32) {
        float s = 0.0f;
#pragma unroll
        for (int ch = 0; ch < 8; ++ch) s += red[ch * 32 + tid];
        out[np0 + tid] = s;
    }
}

// ---------------------------------------------------------------------------
extern "C" void kernel_launch(void* const* d_in, const int* in_sizes, int n_in,
                              void* d_out, int out_size, void* d_ws, size_t ws_size,
                              hipStream_t stream) {
    const float* Xin   = (const float*)d_in[0];
    const float* Z     = (const float*)d_in[1];
    const float* q_mu  = (const float*)d_in[2];
    const float* q_sqrt= (const float*)d_in[3];
    const float* var_p = (const float*)d_in[4];
    const float* ls_p  = (const float*)d_in[5];
    float* out = (float*)d_out;

    float* ws = (float*)d_ws;
    const int MAT = MM * MM;  // 147456
    float* Kuu = ws;
    float* Xa  = ws + 1 * MAT;
    float* Xb  = ws + 2 * MAT;
    float* Ra  = ws + 3 * MAT;
    float* Rb  = ws + 4 * MAT;
    unsigned short* Bfh = (unsigned short*)(ws + 5 * MAT);
    unsigned short* Bfl = Bfh + MAT;
    float* cvec  = (float*)(Bfl + MAT);
    float* alpha = cvec + MM;

    // 1) Kuu
    kuu_kernel<<<(MAT + 255) / 256, 256, 0, stream>>>(Z, var_p, ls_p, Kuu);
    // 2) alpha ; X0 = alpha*I, R0 = I - alpha*Kuu
    rowmax_kernel<<<1, 256, 0, stream>>>(Kuu, alpha);
    init_kernel<<<(MAT + 255) / 256, 256, 0, stream>>>(Kuu, alpha, Xa, Ra);
    // 3) Newton-Schulz rounds: X' = X + X@R ; R' = R@R (one launch each round)
    float* Xc = Xa; float* Rc = Ra; float* Xn = Xb; float* Rn = Rb;
    for (int it = 0; it < NEWTON_ITERS; ++it) {
        ns_round_kernel<<<72, 256, 0, stream>>>(Xc, Rc, Xn, Rn);
        float* t;
        t = Xc; Xc = Xn; Xn = t;
        t = Rc; Rc = Rn; Rn = t;
    }
    // After even #rounds: Xc == Xa holds Kuu^{-1}. Ra/Rb free now.
    float* SKm = Rb;
    float* Y   = Ra;
    float* Bq  = Xb;
    // 4) SK = tril(q_sqrt) tril(q_sqrt)^T - Kuu
    dim3 g12(MM / 32, MM / 32);
    sk_kernel<<<g12, 256, 0, stream>>>(q_sqrt, Kuu, SKm);
    // 5) Bq = X @ SK @ X
    gemm64_kernel<<<36, 256, 0, stream>>>(Xc, SKm, Y);
    gemm64_kernel<<<36, 256, 0, stream>>>(Y, Xc, Bq);
    // 6) c = X @ q_mu
    gemv384_kernel<<<MM, 64, 0, stream>>>(Xc, q_mu, cvec);
    // 7) convert Bq to bf16 hi/lo fragments
    convert_kernel<<<(MAT + 255) / 256, 256, 0, stream>>>(Bq, Bfh, Bfl);
    // 8) fused main kernel
    main_kernel<<<NPTS / TP, 256, 0, stream>>>(Xin, Z, Bfh, Bfl, cvec, var_p, ls_p, out);
}

// Round 3
// 344.700 us; speedup vs baseline: 3.7690x; 1.7274x over previous
//
#include <hip/hip_runtime.h>
#include <hip/hip_bf16.h>

// Problem constants
#define HH 40
#define WW 40
#define KK 5
#define PP 1296            // 36*36
#define LL 25
#define MM 384
#define NN 64
#define NPTS (NN * PP)     // 82944
#define JITTER 1e-6f
#define NS_ITERS 10        // even

typedef unsigned short u16;
typedef unsigned int   u32;
using short8  = __attribute__((ext_vector_type(8))) short;
using floatx4 = __attribute__((ext_vector_type(4))) float;

#define FRAG_N (MM * MM)        // u16 elements per frag array (147456)
#define ZFRAG_N (24 * 64 * 8)   // 12288

// ---------------------------------------------------------------------------
// bf16 split helpers (RNE)
__device__ inline u16 f2bf(float v) {
    u32 b = __float_as_uint(v);
    return (u16)((b + 0x7FFFu + ((b >> 16) & 1u)) >> 16);
}
__device__ inline float bf2f(u16 h) { return __uint_as_float(((u32)h) << 16); }
__device__ inline void split_bf16(float v, u16& hi, u16& lo) {
    hi = f2bf(v);
    lo = f2bf(v - bf2f(hi));
}

// A-fragment linear index (u16 units) for element (m,k) of a 384x384 matrix.
// Layout [mt(24)][kt(12)][lane(64)][j(8)]; m = mt*16+(lane&15), k = kt*32+(lane>>4)*8+j
// (hardware-verified by round-2's passing run)
__device__ inline int frag_idx(int m, int k) {
    return (((m >> 4) * 12 + (k >> 5)) * 64 + ((m & 15) + (((k >> 3) & 3) << 4))) * 8 + (k & 7);
}

// ---------------------------------------------------------------------------
// Kuu[i][j] = var * exp(-0.5*||Zi-Zj||^2/ls^2) + jitter*I  (fp32)
__global__ void kuu_kernel(const float* __restrict__ Z,
                           const float* __restrict__ var_p,
                           const float* __restrict__ ls_p,
                           float* __restrict__ Kuu) {
    int idx = blockIdx.x * 256 + threadIdx.x;
    if (idx >= MM * MM) return;
    int i = idx / MM, j = idx % MM;
    float s = 0.0f;
#pragma unroll
    for (int l = 0; l < LL; ++l) {
        float d = Z[i * LL + l] - Z[j * LL + l];
        s += d * d;
    }
    float ls = ls_p[0];
    float v = var_p[0] * expf(-0.5f * s / (ls * ls));
    if (i == j) v += JITTER;
    Kuu[idx] = v;
}

// rowsum (wave per row), then alpha = 1/max
__global__ void rowsum_kernel(const float* __restrict__ Kuu, float* __restrict__ rs) {
    int gw = blockIdx.x * 4 + (threadIdx.x >> 6);
    int l = threadIdx.x & 63;
    float s = 0.f;
    for (int c = l; c < MM; c += 64) s += Kuu[gw * MM + c];
#pragma unroll
    for (int o = 32; o > 0; o >>= 1) s += __shfl_down(s, o);
    if (l == 0) rs[gw] = s;
}
__global__ void alpha_kernel(const float* __restrict__ rs, float* __restrict__ alpha) {
    __shared__ float red[256];
    float mx = 0.f;
    for (int r = threadIdx.x; r < MM; r += 256) mx = fmaxf(mx, rs[r]);
    red[threadIdx.x] = mx;
    __syncthreads();
    for (int o = 128; o > 0; o >>= 1) {
        if (threadIdx.x < o) red[threadIdx.x] = fmaxf(red[threadIdx.x], red[threadIdx.x + o]);
        __syncthreads();
    }
    if (threadIdx.x == 0) alpha[0] = 1.0f / red[0];
}

// X0 = alpha*I ; R0 = I - alpha*Kuu   (both written as frag hi/lo)
__global__ void init_frag_kernel(const float* __restrict__ Kuu,
                                 const float* __restrict__ alpha,
                                 u16* __restrict__ Xh, u16* __restrict__ Xl,
                                 u16* __restrict__ Rh, u16* __restrict__ Rl) {
    int o = blockIdx.x * 256 + threadIdx.x;
    if (o >= FRAG_N) return;
    int j = o & 7, ln = (o >> 3) & 63, kt = (o >> 9) % 12, mt = o / 6144;
    int m = mt * 16 + (ln & 15);
    int k = kt * 32 + ((ln >> 4) << 3) + j;
    float a = alpha[0];
    float dg = (m == k) ? 1.f : 0.f;
    float r0 = dg - a * Kuu[m * MM + k];
    float x0 = (m == k) ? a : 0.f;
    u16 h, lo;
    split_bf16(r0, h, lo); Rh[o] = h; Rl[o] = lo;
    split_bf16(x0, h, lo); Xh[o] = h; Xl[o] = lo;
}

// tril(q_sqrt) as frag hi/lo
__global__ void qs_frag_kernel(const float* __restrict__ qs,
                               u16* __restrict__ Qh, u16* __restrict__ Ql) {
    int o = blockIdx.x * 256 + threadIdx.x;
    if (o >= FRAG_N) return;
    int j = o & 7, ln = (o >> 3) & 63, kt = (o >> 9) % 12, mt = o / 6144;
    int m = mt * 16 + (ln & 15);
    int k = kt * 32 + ((ln >> 4) << 3) + j;
    float v = (k <= m) ? qs[m * MM + k] : 0.f;
    u16 h, lo;
    split_bf16(v, h, lo);
    Qh[o] = h; Ql[o] = lo;
}

// Z fragments (A-operand of the phase-1 cross GEMM, K padded 25->32) + z^2
__global__ void zfrag_kernel(const float* __restrict__ Z,
                             u16* __restrict__ Zfh, u16* __restrict__ Zfl) {
    int o = blockIdx.x * 256 + threadIdx.x;
    if (o >= ZFRAG_N) return;
    int j = o & 7, ln = (o >> 3) & 63, zt = o >> 9;
    int m = zt * 16 + (ln & 15);
    int kd = ((ln >> 4) << 3) + j;
    float v = (kd < LL) ? Z[m * LL + kd] : 0.f;
    u16 h, lo;
    split_bf16(v, h, lo);
    Zfh[o] = h; Zfl[o] = lo;
}
__global__ void z2_kernel(const float* __restrict__ Z, float* __restrict__ z2g) {
    int m = blockIdx.x * 256 + threadIdx.x;
    if (m >= MM) return;
    float s = 0.f;
#pragma unroll
    for (int l = 0; l < LL; ++l) { float z = Z[m * LL + l]; s += z * z; }
    z2g[m] = s;
}

// ---------------------------------------------------------------------------
// Shared split-bf16 MFMA 64x64-tile GEMM body on frag operands.
// B must be symmetric (B-frag short8 == its A-frag short8 at same lane).
__device__ inline void frag_gemm64(const u16* __restrict__ Ah, const u16* __restrict__ Al,
                                   const u16* __restrict__ Bh, const u16* __restrict__ Bl,
                                   int bi, int bj, int w, int l, floatx4 acc[2][2]) {
    int mt0 = bi * 4 + 2 * (w & 1);
    int nt0 = bj * 4 + 2 * (w >> 1);
#pragma unroll
    for (int i = 0; i < 2; ++i)
#pragma unroll
        for (int jn = 0; jn < 2; ++jn) { floatx4 z = {0.f, 0.f, 0.f, 0.f}; acc[i][jn] = z; }
    for (int kt = 0; kt < 12; ++kt) {
        int ab0 = (((mt0 + 0) * 12 + kt) * 64 + l) * 8;
        int ab1 = (((mt0 + 1) * 12 + kt) * 64 + l) * 8;
        int bb0 = (((nt0 + 0) * 12 + kt) * 64 + l) * 8;
        int bb1 = (((nt0 + 1) * 12 + kt) * 64 + l) * 8;
        short8 a0h = *(const short8*)&Ah[ab0];
        short8 a0l = *(const short8*)&Al[ab0];
        short8 a1h = *(const short8*)&Ah[ab1];
        short8 a1l = *(const short8*)&Al[ab1];
        short8 b0h = *(const short8*)&Bh[bb0];
        short8 b0l = *(const short8*)&Bl[bb0];
        short8 b1h = *(const short8*)&Bh[bb1];
        short8 b1l = *(const short8*)&Bl[bb1];
        acc[0][0] = __builtin_amdgcn_mfma_f32_16x16x32_bf16(a0h, b0h, acc[0][0], 0, 0, 0);
        acc[0][0] = __builtin_amdgcn_mfma_f32_16x16x32_bf16(a0h, b0l, acc[0][0], 0, 0, 0);
        acc[0][0] = __builtin_amdgcn_mfma_f32_16x16x32_bf16(a0l, b0h, acc[0][0], 0, 0, 0);
        acc[0][1] = __builtin_amdgcn_mfma_f32_16x16x32_bf16(a0h, b1h, acc[0][1], 0, 0, 0);
        acc[0][1] = __builtin_amdgcn_mfma_f32_16x16x32_bf16(a0h, b1l, acc[0][1], 0, 0, 0);
        acc[0][1] = __builtin_amdgcn_mfma_f32_16x16x32_bf16(a0l, b1h, acc[0][1], 0, 0, 0);
        acc[1][0] = __builtin_amdgcn_mfma_f32_16x16x32_bf16(a1h, b0h, acc[1][0], 0, 0, 0);
        acc[1][0] = __builtin_amdgcn_mfma_f32_16x16x32_bf16(a1h, b0l, acc[1][0], 0, 0, 0);
        acc[1][0] = __builtin_amdgcn_mfma_f32_16x16x32_bf16(a1l, b0h, acc[1][0], 0, 0, 0);
        acc[1][1] = __builtin_amdgcn_mfma_f32_16x16x32_bf16(a1h, b1h, acc[1][1], 0, 0, 0);
        acc[1][1] = __builtin_amdgcn_mfma_f32_16x16x32_bf16(a1h, b1l, acc[1][1], 0, 0, 0);
        acc[1][1] = __builtin_amdgcn_mfma_f32_16x16x32_bf16(a1l, b1h, acc[1][1], 0, 0, 0);
    }
}

__device__ inline void dwrite_frag(u16* __restrict__ Oh, u16* __restrict__ Ol,
                                   int m, int p, float v) {
    int idx = frag_idx(m, p);
    u16 hi, lo;
    split_bf16(v, hi, lo);
    Oh[idx] = hi; Ol[idx] = lo;
}

// One Newton-Schulz round: blocks 0..35 -> X' = X + X@R; 36..71 -> R' = R@R
__global__ void __launch_bounds__(256) ns_frag_kernel(
    const u16* __restrict__ Xh, const u16* __restrict__ Xl,
    const u16* __restrict__ Rh, const u16* __restrict__ Rl,
    u16* __restrict__ nXh, u16* __restrict__ nXl,
    u16* __restrict__ nRh, u16* __restrict__ nRl) {
    int t = blockIdx.x;
    bool isX = (t < 36);
    int tile = isX ? t : t - 36;
    int bi = tile / 6, bj = tile % 6;
    int w = threadIdx.x >> 6, l = threadIdx.x & 63;
    floatx4 acc[2][2];
    frag_gemm64(isX ? Xh : Rh, isX ? Xl : Rl, Rh, Rl, bi, bj, w, l, acc);
    int mt0 = bi * 4 + 2 * (w & 1), nt0 = bj * 4 + 2 * (w >> 1);
    u16* Oh = isX ? nXh : nRh;
    u16* Ol = isX ? nXl : nRl;
#pragma unroll
    for (int i = 0; i < 2; ++i)
#pragma unroll
        for (int jn = 0; jn < 2; ++jn)
#pragma unroll
            for (int j = 0; j < 4; ++j) {
                int m = (mt0 + i) * 16 + ((l >> 4) << 2) + j;
                int p = (nt0 + jn) * 16 + (l & 15);
                float v = acc[i][jn][j];
                if (isX) {
                    int id = frag_idx(m, p);
                    v += bf2f(Xh[id]) + bf2f(Xl[id]);
                }
                dwrite_frag(Oh, Ol, m, p, v);
            }
}

// SK = tril(qs) tril(qs)^T - Kuu  (frag out)
__global__ void __launch_bounds__(256) sk_frag_kernel(
    const u16* __restrict__ Qh, const u16* __restrict__ Ql,
    const float* __restrict__ Kuu,
    u16* __restrict__ SKh, u16* __restrict__ SKl) {
    int bi = blockIdx.x / 6, bj = blockIdx.x % 6;
    int w = threadIdx.x >> 6, l = threadIdx.x & 63;
    floatx4 acc[2][2];
    frag_gemm64(Qh, Ql, Qh, Ql, bi, bj, w, l, acc);
    int mt0 = bi * 4 + 2 * (w & 1), nt0 = bj * 4 + 2 * (w >> 1);
#pragma unroll
    for (int i = 0; i < 2; ++i)
#pragma unroll
        for (int jn = 0; jn < 2; ++jn)
#pragma unroll
            for (int j = 0; j < 4; ++j) {
                int m = (mt0 + i) * 16 + ((l >> 4) << 2) + j;
                int p = (nt0 + jn) * 16 + (l & 15);
                dwrite_frag(SKh, SKl, m, p, acc[i][jn][j] - Kuu[m * MM + p]);
            }
}

// C = A @ B (B symmetric), frag in/out. Used for Y = X@SK and Bq = Y@X.
__global__ void __launch_bounds__(256) mm_frag_kernel(
    const u16* __restrict__ Ah, const u16* __restrict__ Al,
    const u16* __restrict__ Bh, const u16* __restrict__ Bl,
    u16* __restrict__ Ch, u16* __restrict__ Cl) {
    int bi = blockIdx.x / 6, bj = blockIdx.x % 6;
    int w = threadIdx.x >> 6, l = threadIdx.x & 63;
    floatx4 acc[2][2];
    frag_gemm64(Ah, Al, Bh, Bl, bi, bj, w, l, acc);
    int mt0 = bi * 4 + 2 * (w & 1), nt0 = bj * 4 + 2 * (w >> 1);
#pragma unroll
    for (int i = 0; i < 2; ++i)
#pragma unroll
        for (int jn = 0; jn < 2; ++jn)
#pragma unroll
            for (int j = 0; j < 4; ++j) {
                int m = (mt0 + i) * 16 + ((l >> 4) << 2) + j;
                int p = (nt0 + jn) * 16 + (l & 15);
                dwrite_frag(Ch, Cl, m, p, acc[i][jn][j]);
            }
}

// cvec = X @ q_mu from frag X
__global__ void __launch_bounds__(256) cvec_kernel(
    const u16* __restrict__ Xh, const u16* __restrict__ Xl,
    const float* __restrict__ qmu, float* __restrict__ cvec) {
    __shared__ float q[MM];
    int tid = threadIdx.x;
    if (tid < MM) q[tid] = qmu[tid];
    if (tid + 256 < MM) q[tid + 256] = qmu[tid + 256];
    __syncthreads();
    int w = tid >> 6, l = tid & 63;
    int mt = blockIdx.x * 4 + w;
    float s = 0.f;
    for (int kt = 0; kt < 12; ++kt) {
        int b = ((mt * 12 + kt) * 64 + l) * 8;
        short8 h8 = *(const short8*)&Xh[b];
        short8 l8 = *(const short8*)&Xl[b];
        int kb = kt * 32 + ((l >> 4) << 3);
        float4 q0 = *(const float4*)&q[kb];
        float4 q1 = *(const float4*)&q[kb + 4];
        float qv[8] = {q0.x, q0.y, q0.z, q0.w, q1.x, q1.y, q1.z, q1.w};
#pragma unroll
        for (int j = 0; j < 8; ++j)
            s += (bf2f((u16)h8[j]) + bf2f((u16)l8[j])) * qv[j];
    }
    s += __shfl_xor(s, 16);
    s += __shfl_xor(s, 32);
    if (l < 16) cvec[mt * 16 + l] = s;
}

// ---------------------------------------------------------------------------
// Main fused kernel, TP=64 points, 512 threads (8 waves).
// K-tile LDS: B-frag layout, granule(k,p)=((k>>5)*4+(p>>4))*64+((k>>3)&3)*16+(p&15),
// padded +8 u16 per 16 granules to break store bank conflicts.
#define KPAD 26112   // 3072 granules * 8 + 192 pads * 8

__device__ inline int lds_k_off(int g, int sidx) { return g * 8 + ((g >> 4) << 3) + sidx; }
__device__ inline int k_granule(int k, int p) {
    return ((k >> 5) * 4 + (p >> 4)) * 64 + (((k >> 3) & 3) << 4) + (p & 15);
}

__global__ void __launch_bounds__(512) main_kernel(
    const float* __restrict__ Xin,
    const u16* __restrict__ Zfh, const u16* __restrict__ Zfl,
    const float* __restrict__ z2g,
    const u16* __restrict__ Bfh, const u16* __restrict__ Bfl,
    const float* __restrict__ cvec,
    const float* __restrict__ var_p, const float* __restrict__ ls_p,
    float* __restrict__ out) {
    __shared__ float patch[64 * 36];
    __shared__ float zsq[MM];
    __shared__ float xsq[64];
    __shared__ u16 kh[KPAD];
    __shared__ u16 kl[KPAD];
    __shared__ float red[512];

    int tid = threadIdx.x;
    int np0 = blockIdx.x * 64;
    float var = var_p[0];
    float ls = ls_p[0];
    float c0 = -0.5f / (ls * ls);

    // stage z^2 and patches (cols 25..35 zeroed)
    if (tid < MM) zsq[tid] = z2g[tid];
    for (int e = tid; e < 64 * 36; e += 512) {
        int pt = e / 36, c = e % 36;
        float v = 0.f;
        if (c < 25) {
            int np = np0 + pt;
            int n = np / PP, p = np % PP;
            int oi = p / 36, oj = p % 36;
            v = Xin[n * (HH * WW) + (oi + c / 5) * WW + (oj + c % 5)];
        }
        patch[e] = v;
    }
    __syncthreads();
    if (tid < 64) {
        float s = 0.f;
#pragma unroll
        for (int l2 = 0; l2 < LL; ++l2) { float x = patch[tid * 36 + l2]; s += x * x; }
        xsq[tid] = s;
    }
    __syncthreads();

    int w = tid >> 6, l = tid & 63;

    // phase 1: cross = Z @ patch^T via split-bf16 MFMA, then K = var*exp(c0*dist2)
    short8 pbh[4], pbl[4];
#pragma unroll
    for (int nt = 0; nt < 4; ++nt) {
        int p = nt * 16 + (l & 15);
        int pb = p * 36 + ((l >> 4) << 3);
        float4 f0 = *(const float4*)&patch[pb];
        float4 f1 = *(const float4*)&patch[pb + 4];
        float xv[8] = {f0.x, f0.y, f0.z, f0.w, f1.x, f1.y, f1.z, f1.w};
#pragma unroll
        for (int j = 0; j < 8; ++j) {
            u16 h, lo;
            split_bf16(xv[j], h, lo);
            pbh[nt][j] = (short)h;
            pbl[nt][j] = (short)lo;
        }
    }
    floatx4 acc2[3][4];
#pragma unroll
    for (int i = 0; i < 3; ++i) {
        int zt = w * 3 + i;
        short8 zah = *(const short8*)&Zfh[(zt * 64 + l) * 8];
        short8 zal = *(const short8*)&Zfl[(zt * 64 + l) * 8];
#pragma unroll
        for (int nt = 0; nt < 4; ++nt) {
            floatx4 z = {0.f, 0.f, 0.f, 0.f};
            z = __builtin_amdgcn_mfma_f32_16x16x32_bf16(zah, pbh[nt], z, 0, 0, 0);
            z = __builtin_amdgcn_mfma_f32_16x16x32_bf16(zah, pbl[nt], z, 0, 0, 0);
            z = __builtin_amdgcn_mfma_f32_16x16x32_bf16(zal, pbh[nt], z, 0, 0, 0);
            acc2[i][nt] = z;
        }
    }
#pragma unroll
    for (int i = 0; i < 3; ++i) {
        int k0 = (w * 3 + i) * 16 + ((l >> 4) << 2);
#pragma unroll
        for (int nt = 0; nt < 4; ++nt) {
            int p = nt * 16 + (l & 15);
            u16 hi[4], lo[4];
#pragma unroll
            for (int j = 0; j < 4; ++j) {
                float s = zsq[k0 + j] + xsq[p] - 2.f * acc2[i][nt][j];
                s = fmaxf(s, 0.f);
                float v = var * __expf(s * c0);
                split_bf16(v, hi[j], lo[j]);
            }
            int g = k_granule(k0, p);
            int off = lds_k_off(g, k0 & 7);
            *(u32*)&kh[off]     = (u32)hi[0] | ((u32)hi[1] << 16);
            *(u32*)&kh[off + 2] = (u32)hi[2] | ((u32)hi[3] << 16);
            *(u32*)&kl[off]     = (u32)lo[0] | ((u32)lo[1] << 16);
            *(u32*)&kl[off + 2] = (u32)lo[2] | ((u32)lo[3] << 16);
        }
    }
    __syncthreads();

    // phase 2: acc[m][p] = sum_k Bq[m][k] K[k][p], 3-term split-bf16 MFMA
    floatx4 acc[3][4];
#pragma unroll
    for (int i = 0; i < 3; ++i)
#pragma unroll
        for (int nt = 0; nt < 4; ++nt) { floatx4 z = {0.f, 0.f, 0.f, 0.f}; acc[i][nt] = z; }
    for (int kt = 0; kt < 12; ++kt) {
        short8 bh[4], bl[4];
#pragma unroll
        for (int nt = 0; nt < 4; ++nt) {
            int g = (kt * 4 + nt) * 64 + l;
            int off = lds_k_off(g, 0);
            bh[nt] = *(const short8*)&kh[off];
            bl[nt] = *(const short8*)&kl[off];
        }
#pragma unroll
        for (int i = 0; i < 3; ++i) {
            int mt = w * 3 + i;
            int ab = ((mt * 12 + kt) * 64 + l) * 8;
            short8 ah = *(const short8*)&Bfh[ab];
            short8 al = *(const short8*)&Bfl[ab];
#pragma unroll
            for (int nt = 0; nt < 4; ++nt) {
                acc[i][nt] = __builtin_amdgcn_mfma_f32_16x16x32_bf16(ah, bh[nt], acc[i][nt], 0, 0, 0);
                acc[i][nt] = __builtin_amdgcn_mfma_f32_16x16x32_bf16(ah, bl[nt], acc[i][nt], 0, 0, 0);
                acc[i][nt] = __builtin_amdgcn_mfma_f32_16x16x32_bf16(al, bh[nt], acc[i][nt], 0, 0, 0);
            }
        }
    }

    // epilogue: diag[p] = sum_m K[m][p] * acc[m][p]
    float dp[4] = {0.f, 0.f, 0.f, 0.f};
#pragma unroll
    for (int i = 0; i < 3; ++i)
#pragma unroll
        for (int j = 0; j < 4; ++j) {
            int m = (w * 3 + i) * 16 + ((l >> 4) << 2) + j;
#pragma unroll
            for (int nt = 0; nt < 4; ++nt) {
                int p = nt * 16 + (l & 15);
                int off = lds_k_off(k_granule(m, p), m & 7);
                float kv = bf2f(kh[off]) + bf2f(kl[off]);
                dp[nt] += kv * acc[i][nt][j];
            }
        }
#pragma unroll
    for (int nt = 0; nt < 4; ++nt) {
        dp[nt] += __shfl_xor(dp[nt], 16);
        dp[nt] += __shfl_xor(dp[nt], 32);
    }
    if (l < 16) {
#pragma unroll
        for (int nt = 0; nt < 4; ++nt) red[w * 64 + nt * 16 + l] = dp[nt];
    }
    __syncthreads();
    if (tid < 64) {
        float s = 0.f;
#pragma unroll
        for (int ww = 0; ww < 8; ++ww) s += red[ww * 64 + tid];
        out[NPTS + np0 + tid] = var + s;
    }
    __syncthreads();

    // mean[p] = sum_m cvec[m] * K[m][p]
    {
        int p = tid & 63, mg = tid >> 6;
        float s = 0.f;
        for (int i = 0; i < 48; ++i) {
            int m = mg * 48 + i;
            int off = lds_k_off(k_granule(m, p), m & 7);
            s += cvec[m] * (bf2f(kh[off]) + bf2f(kl[off]));
        }
        red[mg * 64 + p] = s;
    }
    __syncthreads();
    if (tid < 64) {
        float s = 0.f;
#pragma unroll
        for (int mg = 0; mg < 8; ++mg) s += red[mg * 64 + tid];
        out[np0 + tid] = s;
    }
}

// ---------------------------------------------------------------------------
extern "C" void kernel_launch(void* const* d_in, const int* in_sizes, int n_in,
                              void* d_out, int out_size, void* d_ws, size_t ws_size,
                              hipStream_t stream) {
    const float* Xin    = (const float*)d_in[0];
    const float* Z      = (const float*)d_in[1];
    const float* q_mu   = (const float*)d_in[2];
    const float* q_sqrt = (const float*)d_in[3];
    const float* var_p  = (const float*)d_in[4];
    const float* ls_p   = (const float*)d_in[5];
    float* out = (float*)d_out;

    const size_t HB = (size_t)FRAG_N * 2;  // bytes per frag half array (294912)
    char* base = (char*)d_ws;
    // region A: Kuu fp32, later overlaid by Y frags
    float* Kuu = (float*)base;
    u16* Yh = (u16*)base;
    u16* Yl = (u16*)(base + HB);
    char* pB = base + 2 * HB;            // X ping-pong (4 half arrays)
    u16* Xh_a = (u16*)(pB + 0 * HB);
    u16* Xl_a = (u16*)(pB + 1 * HB);
    u16* Xh_b = (u16*)(pB + 2 * HB);
    u16* Xl_b = (u16*)(pB + 3 * HB);
    char* pC = pB + 4 * HB;              // R ping-pong, later Q/SK frags
    u16* Rh_a = (u16*)(pC + 0 * HB);
    u16* Rl_a = (u16*)(pC + 1 * HB);
    u16* Rh_b = (u16*)(pC + 2 * HB);
    u16* Rl_b = (u16*)(pC + 3 * HB);
    u16* Qh = Rh_a; u16* Ql = Rl_a;
    u16* SKh = Rh_b; u16* SKl = Rl_b;
    char* pE = pC + 4 * HB;              // Bq frags for main kernel
    u16* Bfh = (u16*)(pE + 0 * HB);
    u16* Bfl = (u16*)(pE + 1 * HB);
    char* pF = pE + 2 * HB;
    u16* Zfh = (u16*)pF;
    u16* Zfl = (u16*)(pF + ZFRAG_N * 2);
    float* z2g   = (float*)(pF + ZFRAG_N * 4);
    float* cvec  = z2g + MM;
    float* rsum  = cvec + MM;
    float* alpha = rsum + MM;

    kuu_kernel<<<(MM * MM + 255) / 256, 256, 0, stream>>>(Z, var_p, ls_p, Kuu);
    z2_kernel<<<2, 256, 0, stream>>>(Z, z2g);
    zfrag_kernel<<<(ZFRAG_N + 255) / 256, 256, 0, stream>>>(Z, Zfh, Zfl);
    rowsum_kernel<<<96, 256, 0, stream>>>(Kuu, rsum);
    alpha_kernel<<<1, 256, 0, stream>>>(rsum, alpha);
    init_frag_kernel<<<(FRAG_N + 255) / 256, 256, 0, stream>>>(Kuu, alpha, Xh_a, Xl_a, Rh_a, Rl_a);

    u16 *Xch = Xh_a, *Xcl = Xl_a, *Xnh = Xh_b, *Xnl = Xl_b;
    u16 *Rch = Rh_a, *Rcl = Rl_a, *Rnh = Rh_b, *Rnl = Rl_b;
    for (int it = 0; it < NS_ITERS; ++it) {
        ns_frag_kernel<<<72, 256, 0, stream>>>(Xch, Xcl, Rch, Rcl, Xnh, Xnl, Rnh, Rnl);
        u16* t;
        t = Xch; Xch = Xnh; Xnh = t;
        t = Xcl; Xcl = Xnl; Xnl = t;
        t = Rch; Rch = Rnh; Rnh = t;
        t = Rcl; Rcl = Rnl; Rnl = t;
    }
    // NS_ITERS even -> X in a-slots; R buffers now free for Q/SK.
    qs_frag_kernel<<<(FRAG_N + 255) / 256, 256, 0, stream>>>(q_sqrt, Qh, Ql);
    sk_frag_kernel<<<36, 256, 0, stream>>>(Qh, Ql, Kuu, SKh, SKl);
    mm_frag_kernel<<<36, 256, 0, stream>>>(Xch, Xcl, SKh, SKl, Yh, Yl);   // Y = X @ SK (over Kuu)
    mm_frag_kernel<<<36, 256, 0, stream>>>(Yh, Yl, Xch, Xcl, Bfh, Bfl);   // Bq = Y @ X
    cvec_kernel<<<6, 256, 0, stream>>>(Xch, Xcl, q_mu, cvec);
    main_kernel<<<NPTS / 64, 512, 0, stream>>>(Xin, Zfh, Zfl, z2g, Bfh, Bfl, cvec,
                                               var_p, ls_p, out);
}